// Round 4
// baseline (366.952 us; speedup 1.0000x reference)
//
#include <hip/hip_runtime.h>
#include <math.h>

namespace {

constexpr float kInv512 = 1.0f / 512.0f;

struct cpx { float x, y; };
__device__ __forceinline__ cpx cadd(cpx a, cpx b){ return {a.x+b.x, a.y+b.y}; }
__device__ __forceinline__ cpx csub(cpx a, cpx b){ return {a.x-b.x, a.y-b.y}; }
__device__ __forceinline__ cpx cmul(cpx a, cpx b){ return {a.x*b.x - a.y*b.y, a.x*b.y + a.y*b.x}; }

// multiply by (S<0 ? -i : +i)
template<int S>
__device__ __forceinline__ cpx Jrot(cpx z){
  return (S < 0) ? cpx{ z.y, -z.x } : cpx{ -z.y, z.x };
}

// natural-order 8-point DFT, A[k] = sum_n A[n] * exp(S*2*pi*i*n*k/8)
template<int S>
__device__ __forceinline__ void dft8(cpx* A){
  const float s2 = 0.70710678118654752440f;
  cpx t0=A[0], t1=A[4], t2=A[2], t3=A[6], t4=A[1], t5=A[5], t6=A[3], t7=A[7];
  cpx b0=cadd(t0,t1), b1=csub(t0,t1), b2=cadd(t2,t3), b3=csub(t2,t3);
  cpx b4=cadd(t4,t5), b5=csub(t4,t5), b6=cadd(t6,t7), b7=csub(t6,t7);
  cpx jb3=Jrot<S>(b3), jb7=Jrot<S>(b7);
  cpx c0=cadd(b0,b2), c2=csub(b0,b2), c1=cadd(b1,jb3), c3=csub(b1,jb3);
  cpx c4=cadd(b4,b6), c6=csub(b4,b6), c5=cadd(b5,jb7), c7=csub(b5,jb7);
  cpx jc6=Jrot<S>(c6);
  cpx w5, w7;
  if (S < 0) {
    w5 = cpx{ s2*(c5.x + c5.y), s2*(c5.y - c5.x) };   // w8^1 * c5
    w7 = cpx{ s2*(c7.y - c7.x), -s2*(c7.x + c7.y) };  // w8^3 * c7
  } else {
    w5 = cpx{ s2*(c5.x - c5.y), s2*(c5.x + c5.y) };
    w7 = cpx{ -s2*(c7.x + c7.y), s2*(c7.x - c7.y) };
  }
  A[0]=cadd(c0,c4); A[4]=csub(c0,c4);
  A[2]=cadd(c2,jc6); A[6]=csub(c2,jc6);
  A[1]=cadd(c1,w5);  A[5]=csub(c1,w5);
  A[3]=cadd(c3,w7);  A[7]=csub(c3,w7);
}

// LDS slot for "natural" index n within one pair's buffer (rows of 66 float2,
// rotated by row to keep all within-wave access patterns bank-uniform)
__device__ __forceinline__ int slotN(int n){
  int row = n >> 6;
  return 66*row + (((n & 63) + row) & 63);
}

// In-place 512-point complex FFT over one wave (64 lanes x 8 regs).
// Input natural order, output natural order (via slotN addressing).
// S = -1 forward, +1 inverse (unnormalized).
// NO barriers inside: the buffer zp is WAVE-PRIVATE during the FFT; CDNA LDS
// ops are in-order per wave, so per-wave read-after-write is safe.
template<int S>
__device__ void fft512(float2* zp, int l){
  cpx a[8];
  // stage 1: n = 64*j + l, in-register DFT8 over j
  #pragma unroll
  for (int j=0;j<8;++j){
    float2 v = zp[66*j + ((l + j) & 63)];
    a[j].x = v.x; a[j].y = v.y;
  }
  dft8<S>(a);
  { // twiddle W512^{l*k}
    float ang = (float)S * 6.28318530717958647692f * (1.0f/512.0f) * (float)l;
    float sn, cn; __sincosf(ang, &sn, &cn);
    cpx w1 = cpx{cn, sn}; cpx wk = w1;
    a[1] = cmul(a[1], w1);
    #pragma unroll
    for (int k=2;k<8;++k){ wk = cmul(wk, w1); a[k] = cmul(a[k], wk); }
  }
  #pragma unroll
  for (int k1=0;k1<8;++k1) zp[66*k1 + ((l + k1) & 63)] = make_float2(a[k1].x, a[k1].y);
  // stage 2: lane = (k1, b); DFT8 over a-digit; twiddle W64^{b*c}
  int k1r = l >> 3, d3 = l & 7;
  #pragma unroll
  for (int aa=0;aa<8;++aa){
    float2 v = zp[66*k1r + ((8*aa + d3 + k1r) & 63)];
    a[aa].x = v.x; a[aa].y = v.y;
  }
  dft8<S>(a);
  {
    float ang = (float)S * 6.28318530717958647692f * (1.0f/64.0f) * (float)d3;
    float sn, cn; __sincosf(ang, &sn, &cn);
    cpx w1 = cpx{cn, sn}; cpx wk = w1;
    a[1] = cmul(a[1], w1);
    #pragma unroll
    for (int c=2;c<8;++c){ wk = cmul(wk, w1); a[c] = cmul(a[c], wk); }
  }
  #pragma unroll
  for (int c=0;c<8;++c) zp[66*k1r + ((8*c + d3 + k1r) & 63)] = make_float2(a[c].x, a[c].y);
  // stage 3: lane = (k1, c); DFT8 over b-digit -> output digit d
  #pragma unroll
  for (int b8=0;b8<8;++b8){
    float2 v = zp[66*k1r + ((8*d3 + b8 + k1r) & 63)];
    a[b8].x = v.x; a[b8].y = v.y;
  }
  dft8<S>(a);
  // write natural: k = k1 + 8*c + 64*d
  int klow = k1r + 8*d3;
  #pragma unroll
  for (int d=0;d<8;++d){
    zp[66*d + ((klow + d) & 63)] = make_float2(a[d].x, a[d].y);
  }
}

// ------------- kernel 1: gate = softmax(mean-pool MLP) / 512, single HBM pass -------------
__global__ __launch_bounds__(256) void gate_kernel(
    const float* __restrict__ x, const float* __restrict__ mlp_w,
    const float* __restrict__ mlp_b, float* __restrict__ gate)
{
  __shared__ float tile[32][257];   // 32-row chunk, padded (+1) -> conflict-free
  __shared__ float red[32];
  __shared__ int icnt[4];
  int b = blockIdx.x, t = threadIdx.x;
  const float* xb = x + (size_t)b * 131072;  // 512*256

  float colsum = 0.f;
  int cnt = 0;
  for (int ch = 0; ch < 16; ++ch){
    // coalesced read of 32 rows; accumulate colsum for h=t; stage into LDS
    #pragma unroll
    for (int sr = 0; sr < 32; ++sr){
      float v = xb[(ch*32 + sr)*256 + t];
      colsum += v;
      tile[sr][t] = v;
    }
    __syncthreads();
    // row sums from LDS: 8 threads per row, 32 elements each (conflict-free:
    // bank = (row + j) & 31, rows distinct per fixed j)
    {
      int row = t >> 3, base = (t & 7) * 32;
      float rs = 0.f;
      #pragma unroll
      for (int j = 0; j < 32; ++j) rs += tile[row][base + j];
      rs += __shfl_xor(rs, 1);
      rs += __shfl_xor(rs, 2);
      rs += __shfl_xor(rs, 4);
      if ((t & 7) == 0) cnt += (rs != 0.f) ? 1 : 0;
    }
    __syncthreads();
  }

  // block-reduce valid-row count
  for (int m=1;m<64;m<<=1) cnt += __shfl_xor(cnt, m);
  int wv = t >> 6, ln = t & 63;
  if (ln == 0) icnt[wv] = cnt;
  __syncthreads();
  float valid = (float)(icnt[0]+icnt[1]+icnt[2]+icnt[3]);
  float gi = colsum * (50.0f / ((valid + 1e-4f) * 512.0f));

  // logits: gi (per-h) dot mlp_w[h][e]
  float pl[8];
  const float4* w4 = (const float4*)(mlp_w + (size_t)t*8);
  float4 wa = w4[0], wb = w4[1];
  pl[0]=gi*wa.x; pl[1]=gi*wa.y; pl[2]=gi*wa.z; pl[3]=gi*wa.w;
  pl[4]=gi*wb.x; pl[5]=gi*wb.y; pl[6]=gi*wb.z; pl[7]=gi*wb.w;
  #pragma unroll
  for (int e=0;e<8;++e){
    float v = pl[e];
    for (int m=1;m<64;m<<=1) v += __shfl_xor(v, m);
    pl[e] = v;
  }
  if (ln == 0){
    #pragma unroll
    for (int e=0;e<8;++e) red[wv*8+e] = pl[e];
  }
  __syncthreads();
  if (t < 8){
    float lg = red[0*8+t]+red[1*8+t]+red[2*8+t]+red[3*8+t] + mlp_b[t];
    float mx = lg;
    for (int m=1;m<8;m<<=1) mx = fmaxf(mx, __shfl_xor(mx, m, 8));
    float ex = expf(lg - mx);
    float sm = ex;
    for (int m=1;m<8;m<<=1) sm += __shfl_xor(sm, m, 8);
    gate[b*8 + t] = ex / sm * kInv512;   // fold ortho^2 = 1/512 scaling here
  }
}

// ------------- kernel 2: per (b, 16-channel group): FFT * (1+w) -> h -----------
__global__ __launch_bounds__(512, 8) void fft_kernel(
    const float* __restrict__ x, const float* __restrict__ cw,
    const float* __restrict__ gate, float* __restrict__ out)
{
  __shared__ float2 zz[8][532];   // 8 pairs, stride 532 float2 (33 KB)
  int t = threadIdx.x;
  int hg = blockIdx.x, b = blockIdx.y;
  int h_base = hg * 16;
  const float* xb = x + (size_t)b * 131072;
  float* ob = out + (size_t)b * 131072;

  // gate values (uniform per block) — load early to hide latency under FFT
  float g[8];
  #pragma unroll
  for (int e=0;e<8;++e) g[e] = gate[b*8 + e];

  // phase A: float2 coalesced load (8 lanes x 8B = 64B contiguous chunks);
  // channels (2p, 2p+1) = (re,im) of pair p, one b64 LDS write each.
  #pragma unroll
  for (int it=0; it<8; ++it){
    int s = it*64 + (t >> 3);
    float2 v = *(const float2*)(xb + s*256 + h_base + 2*(t & 7));
    zz[t & 7][slotN(s)] = v;
  }
  __syncthreads();

  int p = t >> 6, l = t & 63;     // wave p handles pair p -> channels h0, h0+1
  float2* zp = zz[p];

  // phase B: forward FFT of packed z = x[:,h0] + i*x[:,h1]
  fft512<-1>(zp, l);
  __syncthreads();

  // phase C (block-cooperative): unpack rfft's, apply (1 + w)/512, repack.
  // item (f, pair): pair = t&7, f = it*64 + (t>>3)  ->  8 consecutive lanes
  // read 8 consecutive float4s of cw = 128B contiguous, fully-used lines.
  {
    int pc = t & 7, fq = t >> 3;
    float2* zq = zz[pc];
    int hc = h_base + 2*pc;
    #pragma unroll
    for (int it=0; it<4; ++it){
      int f = it*64 + fq;                   // 0..255
      float2 Zf = zq[slotN(f)];
      int m = (512 - f) & 511;
      float2 Zm = zq[slotN(m)];
      float X0x = 0.5f*(Zf.x + Zm.x), X0y = 0.5f*(Zf.y - Zm.y);
      float X1x = 0.5f*(Zf.y + Zm.y), X1y = 0.5f*(Zm.x - Zf.x);
      float w0x = kInv512, w0y = 0.f, w1x = kInv512, w1y = 0.f;
      const float* cwf = cw + ((size_t)f*256 + hc)*2;
      #pragma unroll
      for (int e=0;e<8;++e){
        float4 cv = *(const float4*)(cwf + (size_t)e*131584);  // 257*512
        w0x += g[e]*cv.x; w0y += g[e]*cv.y;
        w1x += g[e]*cv.z; w1y += g[e]*cv.w;
      }
      float Y0x = X0x*w0x - X0y*w0y, Y0y = X0x*w0y + X0y*w0x;
      float Y1x = X1x*w1x - X1y*w1y, Y1y = X1x*w1y + X1y*w1x;
      if (f == 0){ Y0y = 0.f; Y1y = 0.f; }  // numpy irfft ignores imag of DC bin
      zq[slotN(f)] = make_float2(Y0x - Y1y, Y0y + Y1x);
      zq[slotN(m)] = make_float2(Y0x + Y1y, Y1x - Y0y);
    }
    if (t < 8){  // Nyquist bin f=256 for pair p=t: imag of products discarded
      float2* zn = zz[t];
      int hn = h_base + 2*t;
      float2 Zf = zn[slotN(256)];
      float w0x = kInv512, w1x = kInv512;
      const float* cwf = cw + ((size_t)256*256 + hn)*2;
      #pragma unroll
      for (int e=0;e<8;++e){
        float4 cv = *(const float4*)(cwf + (size_t)e*131584);
        w0x += g[e]*cv.x; w1x += g[e]*cv.z;
      }
      zn[slotN(256)] = make_float2(Zf.x*w0x, Zf.y*w1x);
    }
  }
  __syncthreads();

  // phase D: inverse FFT -> q = h[:,h0] + i*h[:,h1]   (h = y + x already folded)
  fft512<1>(zp, l);
  __syncthreads();

  // phase E: float2 coalesced writeout (same 64B-chunk pattern as phase A)
  #pragma unroll
  for (int it=0; it<8; ++it){
    int s = it*64 + (t >> 3);
    float2 v = zz[t & 7][slotN(s)];
    *(float2*)(ob + s*256 + h_base + 2*(t & 7)) = v;
  }
}

// ---------------- kernel 3: in-place LayerNorm over H=256 ----------------
__global__ __launch_bounds__(256) void ln_kernel(
    float* __restrict__ io, const float* __restrict__ gamma,
    const float* __restrict__ beta)
{
  int t = threadIdx.x;
  int row = blockIdx.x*4 + (t >> 6);
  int ln = t & 63;
  float4* pr = (float4*)(io + (size_t)row * 256);
  float4 v = pr[ln];
  float s = (v.x+v.y)+(v.z+v.w);
  float q = (v.x*v.x + v.y*v.y) + (v.z*v.z + v.w*v.w);
  for (int m=1;m<64;m<<=1){ s += __shfl_xor(s, m); q += __shfl_xor(q, m); }
  float mean = s * (1.0f/256.0f);
  float var  = q * (1.0f/256.0f) - mean*mean;
  float rstd = rsqrtf(var + 1e-12f);
  const float4 gm = ((const float4*)gamma)[ln];
  const float4 bt = ((const float4*)beta)[ln];
  float4 o;
  o.x = (v.x - mean)*rstd*gm.x + bt.x;
  o.y = (v.y - mean)*rstd*gm.y + bt.y;
  o.z = (v.z - mean)*rstd*gm.z + bt.z;
  o.w = (v.w - mean)*rstd*gm.w + bt.w;
  pr[ln] = o;
}

} // anonymous namespace

extern "C" void kernel_launch(void* const* d_in, const int* in_sizes, int n_in,
                              void* d_out, int out_size, void* d_ws, size_t ws_size,
                              hipStream_t stream) {
  const float* x     = (const float*)d_in[0];
  const float* cw    = (const float*)d_in[1];
  const float* mlp_w = (const float*)d_in[2];
  const float* mlp_b = (const float*)d_in[3];
  const float* gamma = (const float*)d_in[4];
  const float* beta  = (const float*)d_in[5];
  float* out  = (float*)d_out;          // used as h-scratch, then LN'd in place
  float* gate = (float*)d_ws;           // 256*8 floats

  hipLaunchKernelGGL(gate_kernel, dim3(256), dim3(256), 0, stream,
                     x, mlp_w, mlp_b, gate);
  hipLaunchKernelGGL(fft_kernel, dim3(16, 256), dim3(512), 0, stream,
                     x, cw, gate, out);
  hipLaunchKernelGGL(ln_kernel, dim3(32768), dim3(256), 0, stream,
                     out, gamma, beta);
}

// Round 5
// 194.366 us; speedup vs baseline: 1.8879x; 1.8879x over previous
//
#include <hip/hip_runtime.h>
#include <math.h>

namespace {

constexpr float kInv512 = 1.0f / 512.0f;

struct cpx { float x, y; };
__device__ __forceinline__ cpx cadd(cpx a, cpx b){ return {a.x+b.x, a.y+b.y}; }
__device__ __forceinline__ cpx csub(cpx a, cpx b){ return {a.x-b.x, a.y-b.y}; }
__device__ __forceinline__ cpx cmul(cpx a, cpx b){ return {a.x*b.x - a.y*b.y, a.x*b.y + a.y*b.x}; }

// multiply by (S<0 ? -i : +i)
template<int S>
__device__ __forceinline__ cpx Jrot(cpx z){
  return (S < 0) ? cpx{ z.y, -z.x } : cpx{ -z.y, z.x };
}

// natural-order 8-point DFT, A[k] = sum_n A[n] * exp(S*2*pi*i*n*k/8)
template<int S>
__device__ __forceinline__ void dft8(cpx* A){
  const float s2 = 0.70710678118654752440f;
  cpx t0=A[0], t1=A[4], t2=A[2], t3=A[6], t4=A[1], t5=A[5], t6=A[3], t7=A[7];
  cpx b0=cadd(t0,t1), b1=csub(t0,t1), b2=cadd(t2,t3), b3=csub(t2,t3);
  cpx b4=cadd(t4,t5), b5=csub(t4,t5), b6=cadd(t6,t7), b7=csub(t6,t7);
  cpx jb3=Jrot<S>(b3), jb7=Jrot<S>(b7);
  cpx c0=cadd(b0,b2), c2=csub(b0,b2), c1=cadd(b1,jb3), c3=csub(b1,jb3);
  cpx c4=cadd(b4,b6), c6=csub(b4,b6), c5=cadd(b5,jb7), c7=csub(b5,jb7);
  cpx jc6=Jrot<S>(c6);
  cpx w5, w7;
  if (S < 0) {
    w5 = cpx{ s2*(c5.x + c5.y), s2*(c5.y - c5.x) };   // w8^1 * c5
    w7 = cpx{ s2*(c7.y - c7.x), -s2*(c7.x + c7.y) };  // w8^3 * c7
  } else {
    w5 = cpx{ s2*(c5.x - c5.y), s2*(c5.x + c5.y) };
    w7 = cpx{ -s2*(c7.x + c7.y), s2*(c7.x - c7.y) };
  }
  A[0]=cadd(c0,c4); A[4]=csub(c0,c4);
  A[2]=cadd(c2,jc6); A[6]=csub(c2,jc6);
  A[1]=cadd(c1,w5);  A[5]=csub(c1,w5);
  A[3]=cadd(c3,w7);  A[7]=csub(c3,w7);
}

// LDS slot for "natural" index n within one pair's buffer (rows of 66 float2,
// rotated by row to keep all within-wave access patterns bank-uniform)
__device__ __forceinline__ int slotN(int n){
  int row = n >> 6;
  return 66*row + (((n & 63) + row) & 63);
}

// In-place 512-point complex FFT over one wave (64 lanes x 8 regs).
// Input natural order, output natural order (via slotN addressing).
// S = -1 forward, +1 inverse (unnormalized).
// NO barriers inside: the buffer zp is WAVE-PRIVATE during the FFT; CDNA LDS
// ops are in-order per wave, so per-wave read-after-write is safe.
template<int S>
__device__ void fft512(float2* zp, int l){
  cpx a[8];
  // stage 1: n = 64*j + l, in-register DFT8 over j
  #pragma unroll
  for (int j=0;j<8;++j){
    float2 v = zp[66*j + ((l + j) & 63)];
    a[j].x = v.x; a[j].y = v.y;
  }
  dft8<S>(a);
  { // twiddle W512^{l*k}
    float ang = (float)S * 6.28318530717958647692f * (1.0f/512.0f) * (float)l;
    float sn, cn; __sincosf(ang, &sn, &cn);
    cpx w1 = cpx{cn, sn}; cpx wk = w1;
    a[1] = cmul(a[1], w1);
    #pragma unroll
    for (int k=2;k<8;++k){ wk = cmul(wk, w1); a[k] = cmul(a[k], wk); }
  }
  #pragma unroll
  for (int k1=0;k1<8;++k1) zp[66*k1 + ((l + k1) & 63)] = make_float2(a[k1].x, a[k1].y);
  // stage 2: lane = (k1, b); DFT8 over a-digit; twiddle W64^{b*c}
  int k1r = l >> 3, d3 = l & 7;
  #pragma unroll
  for (int aa=0;aa<8;++aa){
    float2 v = zp[66*k1r + ((8*aa + d3 + k1r) & 63)];
    a[aa].x = v.x; a[aa].y = v.y;
  }
  dft8<S>(a);
  {
    float ang = (float)S * 6.28318530717958647692f * (1.0f/64.0f) * (float)d3;
    float sn, cn; __sincosf(ang, &sn, &cn);
    cpx w1 = cpx{cn, sn}; cpx wk = w1;
    a[1] = cmul(a[1], w1);
    #pragma unroll
    for (int c=2;c<8;++c){ wk = cmul(wk, w1); a[c] = cmul(a[c], wk); }
  }
  #pragma unroll
  for (int c=0;c<8;++c) zp[66*k1r + ((8*c + d3 + k1r) & 63)] = make_float2(a[c].x, a[c].y);
  // stage 3: lane = (k1, c); DFT8 over b-digit -> output digit d
  #pragma unroll
  for (int b8=0;b8<8;++b8){
    float2 v = zp[66*k1r + ((8*d3 + b8 + k1r) & 63)];
    a[b8].x = v.x; a[b8].y = v.y;
  }
  dft8<S>(a);
  // write natural: k = k1 + 8*c + 64*d
  int klow = k1r + 8*d3;
  #pragma unroll
  for (int d=0;d<8;++d){
    zp[66*d + ((klow + d) & 63)] = make_float2(a[d].x, a[d].y);
  }
}

// ------------- kernel 1: gate = softmax(mean-pool MLP) / 512, single HBM pass -------------
__global__ __launch_bounds__(256) void gate_kernel(
    const float* __restrict__ x, const float* __restrict__ mlp_w,
    const float* __restrict__ mlp_b, float* __restrict__ gate)
{
  __shared__ float tile[32][257];   // 32-row chunk, padded (+1) -> conflict-free
  __shared__ float red[32];
  __shared__ int icnt[4];
  int b = blockIdx.x, t = threadIdx.x;
  const float* xb = x + (size_t)b * 131072;  // 512*256

  float colsum = 0.f;
  int cnt = 0;
  for (int ch = 0; ch < 16; ++ch){
    // coalesced read of 32 rows; accumulate colsum for h=t; stage into LDS
    #pragma unroll
    for (int sr = 0; sr < 32; ++sr){
      float v = xb[(ch*32 + sr)*256 + t];
      colsum += v;
      tile[sr][t] = v;
    }
    __syncthreads();
    // row sums from LDS: 8 threads per row, 32 elements each (conflict-free:
    // bank = (row + j) & 31, rows distinct per fixed j)
    {
      int row = t >> 3, base = (t & 7) * 32;
      float rs = 0.f;
      #pragma unroll
      for (int j = 0; j < 32; ++j) rs += tile[row][base + j];
      rs += __shfl_xor(rs, 1);
      rs += __shfl_xor(rs, 2);
      rs += __shfl_xor(rs, 4);
      if ((t & 7) == 0) cnt += (rs != 0.f) ? 1 : 0;
    }
    __syncthreads();
  }

  // block-reduce valid-row count
  for (int m=1;m<64;m<<=1) cnt += __shfl_xor(cnt, m);
  int wv = t >> 6, ln = t & 63;
  if (ln == 0) icnt[wv] = cnt;
  __syncthreads();
  float valid = (float)(icnt[0]+icnt[1]+icnt[2]+icnt[3]);
  float gi = colsum * (50.0f / ((valid + 1e-4f) * 512.0f));

  // logits: gi (per-h) dot mlp_w[h][e]
  float pl[8];
  const float4* w4 = (const float4*)(mlp_w + (size_t)t*8);
  float4 wa = w4[0], wb = w4[1];
  pl[0]=gi*wa.x; pl[1]=gi*wa.y; pl[2]=gi*wa.z; pl[3]=gi*wa.w;
  pl[4]=gi*wb.x; pl[5]=gi*wb.y; pl[6]=gi*wb.z; pl[7]=gi*wb.w;
  #pragma unroll
  for (int e=0;e<8;++e){
    float v = pl[e];
    for (int m=1;m<64;m<<=1) v += __shfl_xor(v, m);
    pl[e] = v;
  }
  if (ln == 0){
    #pragma unroll
    for (int e=0;e<8;++e) red[wv*8+e] = pl[e];
  }
  __syncthreads();
  if (t < 8){
    float lg = red[0*8+t]+red[1*8+t]+red[2*8+t]+red[3*8+t] + mlp_b[t];
    float mx = lg;
    for (int m=1;m<8;m<<=1) mx = fmaxf(mx, __shfl_xor(mx, m, 8));
    float ex = expf(lg - mx);
    float sm = ex;
    for (int m=1;m<8;m<<=1) sm += __shfl_xor(sm, m, 8);
    gate[b*8 + t] = ex / sm * kInv512;   // fold ortho^2 = 1/512 scaling here
  }
}

// ------------- kernel 2: per (b, 16-channel group): FFT * (1+w) -> h -----------
// Plain __launch_bounds__(512): round 3/4's (512,8) capped VGPRs at 32 and
// spilled to scratch (FETCH/WRITE blew up 2-4x). 68 VGPRs, zero spill, is the
// proven configuration.
__global__ __launch_bounds__(512) void fft_kernel(
    const float* __restrict__ x, const float* __restrict__ cw,
    const float* __restrict__ gate, float* __restrict__ out)
{
  __shared__ float2 zz[8][532];   // 8 pairs, stride 532 float2 (33 KB)
  int t = threadIdx.x;
  int hg = blockIdx.x, b = blockIdx.y;
  int h_base = hg * 16;
  const float* xb = x + (size_t)b * 131072;
  float* ob = out + (size_t)b * 131072;

  // gate values (uniform per block) — load early to hide latency under FFT
  float g[8];
  #pragma unroll
  for (int e=0;e<8;++e) g[e] = gate[b*8 + e];

  // phase A: float2 coalesced load (8 lanes x 8B = 64B contiguous chunks);
  // channels (2p, 2p+1) = (re,im) of pair p, one b64 LDS write each.
  #pragma unroll
  for (int it=0; it<8; ++it){
    int s = it*64 + (t >> 3);
    float2 v = *(const float2*)(xb + s*256 + h_base + 2*(t & 7));
    zz[t & 7][slotN(s)] = v;
  }
  __syncthreads();

  int p = t >> 6, l = t & 63;     // wave p handles pair p -> channels h0, h0+1
  float2* zp = zz[p];

  // phase B: forward FFT of packed z = x[:,h0] + i*x[:,h1]
  fft512<-1>(zp, l);
  __syncthreads();

  // phase C (block-cooperative): unpack rfft's, apply (1 + w)/512, repack.
  // item (f, pair): pair = t&7, f = it*64 + (t>>3)  ->  8 consecutive lanes
  // read 8 consecutive float4s of cw = 128B contiguous, fully-used lines.
  {
    int pc = t & 7, fq = t >> 3;
    float2* zq = zz[pc];
    int hc = h_base + 2*pc;
    #pragma unroll
    for (int it=0; it<4; ++it){
      int f = it*64 + fq;                   // 0..255
      float2 Zf = zq[slotN(f)];
      int m = (512 - f) & 511;
      float2 Zm = zq[slotN(m)];
      float X0x = 0.5f*(Zf.x + Zm.x), X0y = 0.5f*(Zf.y - Zm.y);
      float X1x = 0.5f*(Zf.y + Zm.y), X1y = 0.5f*(Zm.x - Zf.x);
      float w0x = kInv512, w0y = 0.f, w1x = kInv512, w1y = 0.f;
      const float* cwf = cw + ((size_t)f*256 + hc)*2;
      #pragma unroll
      for (int e=0;e<8;++e){
        float4 cv = *(const float4*)(cwf + (size_t)e*131584);  // 257*512
        w0x += g[e]*cv.x; w0y += g[e]*cv.y;
        w1x += g[e]*cv.z; w1y += g[e]*cv.w;
      }
      float Y0x = X0x*w0x - X0y*w0y, Y0y = X0x*w0y + X0y*w0x;
      float Y1x = X1x*w1x - X1y*w1y, Y1y = X1x*w1y + X1y*w1x;
      if (f == 0){ Y0y = 0.f; Y1y = 0.f; }  // numpy irfft ignores imag of DC bin
      zq[slotN(f)] = make_float2(Y0x - Y1y, Y0y + Y1x);
      zq[slotN(m)] = make_float2(Y0x + Y1y, Y1x - Y0y);
    }
    if (t < 8){  // Nyquist bin f=256 for pair p=t: imag of products discarded
      float2* zn = zz[t];
      int hn = h_base + 2*t;
      float2 Zf = zn[slotN(256)];
      float w0x = kInv512, w1x = kInv512;
      const float* cwf = cw + ((size_t)256*256 + hn)*2;
      #pragma unroll
      for (int e=0;e<8;++e){
        float4 cv = *(const float4*)(cwf + (size_t)e*131584);
        w0x += g[e]*cv.x; w1x += g[e]*cv.z;
      }
      zn[slotN(256)] = make_float2(Zf.x*w0x, Zf.y*w1x);
    }
  }
  __syncthreads();

  // phase D: inverse FFT -> q = h[:,h0] + i*h[:,h1]   (h = y + x already folded)
  fft512<1>(zp, l);
  __syncthreads();

  // phase E: float2 coalesced writeout (same 64B-chunk pattern as phase A)
  #pragma unroll
  for (int it=0; it<8; ++it){
    int s = it*64 + (t >> 3);
    float2 v = zz[t & 7][slotN(s)];
    *(float2*)(ob + s*256 + h_base + 2*(t & 7)) = v;
  }
}

// ---------------- kernel 3: in-place LayerNorm over H=256 ----------------
__global__ __launch_bounds__(256) void ln_kernel(
    float* __restrict__ io, const float* __restrict__ gamma,
    const float* __restrict__ beta)
{
  int t = threadIdx.x;
  int row = blockIdx.x*4 + (t >> 6);
  int ln = t & 63;
  float4* pr = (float4*)(io + (size_t)row * 256);
  float4 v = pr[ln];
  float s = (v.x+v.y)+(v.z+v.w);
  float q = (v.x*v.x + v.y*v.y) + (v.z*v.z + v.w*v.w);
  for (int m=1;m<64;m<<=1){ s += __shfl_xor(s, m); q += __shfl_xor(q, m); }
  float mean = s * (1.0f/256.0f);
  float var  = q * (1.0f/256.0f) - mean*mean;
  float rstd = rsqrtf(var + 1e-12f);
  const float4 gm = ((const float4*)gamma)[ln];
  const float4 bt = ((const float4*)beta)[ln];
  float4 o;
  o.x = (v.x - mean)*rstd*gm.x + bt.x;
  o.y = (v.y - mean)*rstd*gm.y + bt.y;
  o.z = (v.z - mean)*rstd*gm.z + bt.z;
  o.w = (v.w - mean)*rstd*gm.w + bt.w;
  pr[ln] = o;
}

} // anonymous namespace

extern "C" void kernel_launch(void* const* d_in, const int* in_sizes, int n_in,
                              void* d_out, int out_size, void* d_ws, size_t ws_size,
                              hipStream_t stream) {
  const float* x     = (const float*)d_in[0];
  const float* cw    = (const float*)d_in[1];
  const float* mlp_w = (const float*)d_in[2];
  const float* mlp_b = (const float*)d_in[3];
  const float* gamma = (const float*)d_in[4];
  const float* beta  = (const float*)d_in[5];
  float* out  = (float*)d_out;          // used as h-scratch, then LN'd in place
  float* gate = (float*)d_ws;           // 256*8 floats

  hipLaunchKernelGGL(gate_kernel, dim3(256), dim3(256), 0, stream,
                     x, mlp_w, mlp_b, gate);
  hipLaunchKernelGGL(fft_kernel, dim3(16, 256), dim3(512), 0, stream,
                     x, cw, gate, out);
  hipLaunchKernelGGL(ln_kernel, dim3(32768), dim3(256), 0, stream,
                     out, gamma, beta);
}